// Round 17
// baseline (101.551 us; speedup 1.0000x reference)
//
#include <hip/hip_runtime.h>

// Problem constants (from reference setup_inputs).
constexpr int B = 8;
constexpr int N = 16384;
constexpr int M = 1024;
constexpr int C = 256;
constexpr int PTS = 128;  // points per block
constexpr int NW  = 8;    // waves per block (one candidate EIGHTH each)

typedef float vf16 __attribute__((ext_vector_type(16)));

// Block = 512 threads = 8 waves, 1024 blocks -> 4 blocks/CU x 8 waves
// = 32 waves/CU (same occupancy as r10). Wave w scans candidate eighth
// [w*128,(w+1)*128) for TWO points per lane (l and l+64): each SMEM chunk
// (3x s_load_dwordx16 + lgkmcnt wait) is amortized over 2 ladders, and the
// two independent ladder dep-chains interleave (2x ILP). VALU/pair unchanged.
// Selection bit-exact vs reference: d = (dx*dx+dy*dy)+dz*dz separately
// rounded ((c-x) squares identically); strict-< ladder + u64 key merge
// = top_k lowest-index tie-break.
// Phase 2 = r10's proven form (readfirstlane broadcast, float4 gather/store).
// XCD swizzle: batch = blk & 7 pins each batch's 1MB feats to one XCD's L2.
__global__ __launch_bounds__(512, 8) void upsample_idw_kernel(
    const float* __restrict__ xyz,          // [B,N,3]
    const float* __restrict__ sxyz,         // [B,M,3]
    const float* __restrict__ feats,        // [B,M,C]
    const int*   __restrict__ masks,        // [B,N]
    float*       __restrict__ out)          // [B,N,C]
{
    const int tid = threadIdx.x;
    const int w   = tid >> 6;               // wave id = candidate eighth
    const int l   = tid & 63;               // lane
    const int blk = blockIdx.x;
    const int b     = blk & 7;              // batch == XCD (round-robin dispatch)
    const int nbase = (blk >> 3) << 7;      // first point (128 per block)

    __shared__ unsigned long long s_key[PTS][NW][3];   // 24KB
    __shared__ float s_w[PTS][3];
    __shared__ int   s_j[PTS][4];           // j0, j1, j2, valid

    // Two points per lane.
    const float* xpA = xyz + ((size_t)b * N + nbase + l) * 3;
    const float* xpB = xyz + ((size_t)b * N + nbase + 64 + l) * 3;
    const float xA = xpA[0], yA = xpA[1], zA = xpA[2];
    const float xB = xpB[0], yB = xpB[1], zB = xpB[2];

    // BLOCK-uniform batch base (SGPR pair); wave-eighth byte offset via
    // readfirstlane into the SMEM soffset operand.
    const float* bbase = sxyz + (size_t)b * (M * 3);
    const int qoff = __builtin_amdgcn_readfirstlane((tid >> 6) * (128 * 12));

    float a0 = __builtin_inff(), a1 = __builtin_inff(), a2 = __builtin_inff();
    float b0 = __builtin_inff(), b1 = __builtin_inff(), b2 = __builtin_inff();
    int   ia0 = 0, ia1 = 0, ia2 = 0;
    int   ib0 = 0, ib1 = 0, ib2 = 0;

    for (int ch = 0; ch < 8; ++ch) {        // 8 chunks x 16 candidates = 128
        vf16 ca, cb, cc;                    // 48 floats = 16 candidates in SGPRs
        const int off = qoff + ch * 192;    // uniform byte offset
        asm volatile(
            "s_load_dwordx16 %0, %3, %4\n\t"
            "s_load_dwordx16 %1, %3, %4 offset:64\n\t"
            "s_load_dwordx16 %2, %3, %4 offset:128\n\t"
            "s_waitcnt lgkmcnt(0)"
            : "=&s"(ca), "=&s"(cb), "=&s"(cc)
            : "s"(bbase), "s"(off));
        #pragma unroll
        for (int j = 0; j < 16; ++j) {
            const int f0 = 3 * j, f1 = 3 * j + 1, f2 = 3 * j + 2;
            const float cx = (f0 < 16) ? ca[f0 & 15] : (f0 < 32) ? cb[f0 & 15] : cc[f0 & 15];
            const float cy = (f1 < 16) ? ca[f1 & 15] : (f1 < 32) ? cb[f1 & 15] : cc[f1 & 15];
            const float cz = (f2 < 16) ? ca[f2 & 15] : (f2 < 32) ? cb[f2 & 15] : cc[f2 & 15];
            const int m = ch * 16 + j;      // uniform value
            // Point A ((c-x) squares identically to (x-c); separate rounding).
            {
                const float dx = __fsub_rn(cx, xA);
                const float dy = __fsub_rn(cy, yA);
                const float dz = __fsub_rn(cz, zA);
                const float d  = __fadd_rn(__fadd_rn(__fmul_rn(dx, dx), __fmul_rn(dy, dy)),
                                           __fmul_rn(dz, dz));
                const bool lt0 = d < a0, lt1 = d < a1, lt2 = d < a2;
                ia2 = lt1 ? ia1 : (lt2 ? m : ia2);
                ia1 = lt0 ? ia0 : (lt1 ? m : ia1);
                ia0 = lt0 ? m   : ia0;
                const float nd2 = __builtin_amdgcn_fmed3f(a1, a2, d);
                const float nd1 = __builtin_amdgcn_fmed3f(a0, a1, d);
                a2 = nd2; a1 = nd1; a0 = fminf(a0, d);
            }
            // Point B (independent chain -> interleaves with A's).
            {
                const float dx = __fsub_rn(cx, xB);
                const float dy = __fsub_rn(cy, yB);
                const float dz = __fsub_rn(cz, zB);
                const float d  = __fadd_rn(__fadd_rn(__fmul_rn(dx, dx), __fmul_rn(dy, dy)),
                                           __fmul_rn(dz, dz));
                const bool lt0 = d < b0, lt1 = d < b1, lt2 = d < b2;
                ib2 = lt1 ? ib1 : (lt2 ? m : ib2);
                ib1 = lt0 ? ib0 : (lt1 ? m : ib1);
                ib0 = lt0 ? m   : ib0;
                const float nd2 = __builtin_amdgcn_fmed3f(b1, b2, d);
                const float nd1 = __builtin_amdgcn_fmed3f(b0, b1, d);
                b2 = nd2; b1 = nd1; b0 = fminf(b0, d);
            }
        }
    }

    // Pack (dist_bits, global_idx): monotone u64, lowest-index tie-break.
    const unsigned base = (unsigned)(w * 128);
    s_key[l][w][0]      = ((unsigned long long)__float_as_uint(a0) << 32) | (base + (unsigned)ia0);
    s_key[l][w][1]      = ((unsigned long long)__float_as_uint(a1) << 32) | (base + (unsigned)ia1);
    s_key[l][w][2]      = ((unsigned long long)__float_as_uint(a2) << 32) | (base + (unsigned)ia2);
    s_key[l + 64][w][0] = ((unsigned long long)__float_as_uint(b0) << 32) | (base + (unsigned)ib0);
    s_key[l + 64][w][1] = ((unsigned long long)__float_as_uint(b1) << 32) | (base + (unsigned)ib1);
    s_key[l + 64][w][2] = ((unsigned long long)__float_as_uint(b2) << 32) | (base + (unsigned)ib2);
    __syncthreads();

    // ---- Merge: 24 candidates -> top-3 (one thread per point) ----
    if (tid < PTS) {
        unsigned long long k0 = ~0ULL, k1 = ~0ULL, k2 = ~0ULL;
        #pragma unroll
        for (int q = 0; q < NW; ++q) {
            #pragma unroll
            for (int s = 0; s < 3; ++s) {
                const unsigned long long k = s_key[tid][q][s];
                const bool lt0 = k < k0, lt1 = k < k1, lt2 = k < k2;
                k2 = lt1 ? k1 : (lt2 ? k : k2);
                k1 = lt0 ? k0 : (lt1 ? k : k1);
                k0 = lt0 ? k  : k0;
            }
        }
        const float e0 = __uint_as_float((unsigned)(k0 >> 32));
        const float e1 = __uint_as_float((unsigned)(k1 >> 32));
        const float e2 = __uint_as_float((unsigned)(k2 >> 32));
        const float m0 = fmaxf(e0, 1e-10f);
        const float m1 = fmaxf(e1, 1e-10f);
        const float m2 = fmaxf(e2, 1e-10f);
        float w0 = 1.0f / (m0 * m0 + 1e-10f);
        float w1 = 1.0f / (m1 * m1 + 1e-10f);
        float w2 = 1.0f / (m2 * m2 + 1e-10f);
        const int valid = masks[(size_t)b * N + nbase + tid];
        const float scale = valid ? (1.0f / (w0 + w1 + w2)) : 0.0f;
        s_w[tid][0] = w0 * scale;
        s_w[tid][1] = w1 * scale;
        s_w[tid][2] = w2 * scale;
        s_j[tid][0] = (int)(unsigned)k0;
        s_j[tid][1] = (int)(unsigned)k1;
        s_j[tid][2] = (int)(unsigned)k2;
        s_j[tid][3] = valid;
    }
    __syncthreads();

    // ---- Phase 2: 8 points x 64 channel-quads per iteration ----
    const float4* Fb4 = (const float4*)(feats + (size_t)b * (M * C));
    float4* op4 = (float4*)(out + (((size_t)b * N + nbase) * C));

    for (int i = 0; i < 16; ++i) {
        const int p = i * 8 + w;             // wave-uniform point
        const int vld = __builtin_amdgcn_readfirstlane(s_j[p][3]);
        float4 acc = make_float4(0.f, 0.f, 0.f, 0.f);
        if (vld) {                           // scalar branch
            const int j0 = __builtin_amdgcn_readfirstlane(s_j[p][0]);
            const int j1 = __builtin_amdgcn_readfirstlane(s_j[p][1]);
            const int j2 = __builtin_amdgcn_readfirstlane(s_j[p][2]);
            const float w0 = __uint_as_float(
                __builtin_amdgcn_readfirstlane((int)__float_as_uint(s_w[p][0])));
            const float w1 = __uint_as_float(
                __builtin_amdgcn_readfirstlane((int)__float_as_uint(s_w[p][1])));
            const float w2 = __uint_as_float(
                __builtin_amdgcn_readfirstlane((int)__float_as_uint(s_w[p][2])));
            const float4 f0 = Fb4[j0 * 64 + l];
            const float4 f1 = Fb4[j1 * 64 + l];
            const float4 f2 = Fb4[j2 * 64 + l];
            acc.x = fmaf(w2, f2.x, fmaf(w1, f1.x, w0 * f0.x));
            acc.y = fmaf(w2, f2.y, fmaf(w1, f1.y, w0 * f0.y));
            acc.z = fmaf(w2, f2.z, fmaf(w1, f1.z, w0 * f0.z));
            acc.w = fmaf(w2, f2.w, fmaf(w1, f1.w, w0 * f0.w));
        }
        op4[p * 64 + l] = acc;
    }
}

extern "C" void kernel_launch(void* const* d_in, const int* in_sizes, int n_in,
                              void* d_out, int out_size, void* d_ws, size_t ws_size,
                              hipStream_t stream) {
    const float* xyz   = (const float*)d_in[0];
    const float* sxyz  = (const float*)d_in[1];
    const float* feats = (const float*)d_in[2];
    const int*   masks = (const int*)d_in[3];
    float*       out   = (float*)d_out;

    dim3 grid(B * N / PTS);   // 1024 blocks
    dim3 block(512);
    hipLaunchKernelGGL(upsample_idw_kernel, grid, block, 0, stream,
                       xyz, sxyz, feats, masks, out);
}